// Round 1
// baseline (77.950 us; speedup 1.0000x reference)
//
#include <hip/hip_runtime.h>
#include <math.h>

// Problem constants (fixed by setup_inputs):
// B=64, H=W=80, HW=6400, T=50, C=80, D=5+C=85
#define NB    64
#define NH    80
#define NW    80
#define NHW   6400
#define NT    50
#define ND    85
#define NCELL (NB * NHW)   // 409600
#define NTGT  (NB * NT)    // 3200

__device__ __forceinline__ float softplus_f(float x) {
    // matches jax.nn.softplus = logaddexp(x, 0)
    return fmaxf(x, 0.0f) + log1pf(expf(-fabsf(x)));
}

// Kernel 1: scatter obj mask (unique-cell semantics via byte store)
__global__ void mark_kernel(const float* __restrict__ tgt,
                            unsigned char* __restrict__ mask) {
    int i = blockIdx.x * blockDim.x + threadIdx.x;
    if (i >= NTGT) return;
    const float* t = tgt + (size_t)i * 5;
    float cx = t[1], cy = t[2];
    int gx = (int)floorf(cx * (float)NW);
    int gy = (int)floorf(cy * (float)NH);
    int gi = gy * NW + gx;
    int b  = i / NT;
    mask[(size_t)b * NHW + gi] = 1;
}

// Kernel 2: per-target xy/wh/cls losses. One 64-lane wave per target.
__global__ void target_kernel(const float* __restrict__ pred,
                              const float* __restrict__ tgt,
                              float* __restrict__ acc) {
    const int lane   = threadIdx.x & 63;
    const int wib    = threadIdx.x >> 6;
    const int wid    = blockIdx.x * (blockDim.x >> 6) + wib;
    const int nwaves = gridDim.x * (blockDim.x >> 6);

    float coord_sum = 0.0f, cls_sum = 0.0f;

    for (int i = wid; i < NTGT; i += nwaves) {
        int b = i / NT;
        const float* t = tgt + (size_t)i * 5;
        float cid_f = t[0], cx = t[1], cy = t[2], w = t[3], h = t[4];
        int gx = (int)floorf(cx * (float)NW);
        int gy = (int)floorf(cy * (float)NH);
        int gi = gy * NW + gx;
        const float* g = pred + ((size_t)b * NHW + gi) * ND;

        // lane covers element lane, and element 64+lane for lane < 21
        float e0 = g[lane];
        float e1 = (lane < ND - 64) ? g[64 + lane] : 0.0f;

        // log-softmax over class logits g[5..84]
        float v0 = (lane >= 5)      ? e0 : -3.4e38f;
        float v1 = (lane < ND - 64) ? e1 : -3.4e38f;
        float m = fmaxf(v0, v1);
        #pragma unroll
        for (int off = 32; off; off >>= 1) m = fmaxf(m, __shfl_xor(m, off, 64));
        float s = ((lane >= 5)      ? expf(e0 - m) : 0.0f)
                + ((lane < ND - 64) ? expf(e1 - m) : 0.0f);
        #pragma unroll
        for (int off = 32; off; off >>= 1) s += __shfl_xor(s, off, 64);

        // broadcast g[0..3] to all lanes (uniform shfl)
        float g0 = __shfl(e0, 0, 64);
        float g1 = __shfl(e0, 1, 64);
        float g2 = __shfl(e0, 2, 64);
        float g3 = __shfl(e0, 3, 64);

        if (lane == 0) {
            int cid = (int)cid_f;
            float gsel = g[5 + cid];            // cached; cheap re-load
            cls_sum += -(gsel - m - logf(s));   // -log_softmax[cid]

            float px = 1.0f / (1.0f + expf(-g0));
            float py = 1.0f / (1.0f + expf(-g1));
            float tx = cx * (float)NW - (float)gx;
            float ty = cy * (float)NH - (float)gy;
            float tw = logf(w * (float)NW + 1e-16f);
            float th = logf(h * (float)NH + 1e-16f);
            float xy = 0.5f * ((px - tx) * (px - tx) + (py - ty) * (py - ty));
            float wh = 0.5f * ((g2 - tw) * (g2 - tw) + (g3 - th) * (g3 - th));
            coord_sum += xy + wh;
        }
    }

    __shared__ float s_coord, s_cls;
    if (threadIdx.x == 0) { s_coord = 0.0f; s_cls = 0.0f; }
    __syncthreads();
    if (lane == 0) {
        atomicAdd(&s_coord, coord_sum);
        atomicAdd(&s_cls, cls_sum);
    }
    __syncthreads();
    if (threadIdx.x == 0) {
        atomicAdd(&acc[0], s_coord);
        atomicAdd(&acc[1], s_cls);
    }
}

// Kernel 3: confidence sums over all cells (strided conf reads + mask bytes)
__global__ void conf_kernel(const float* __restrict__ pred,
                            const unsigned char* __restrict__ mask,
                            float* __restrict__ acc) {
    int tid    = blockIdx.x * blockDim.x + threadIdx.x;
    int stride = gridDim.x * blockDim.x;

    float obj_s = 0.0f, noobj_s = 0.0f, nobj = 0.0f;
    for (int c = tid; c < NCELL; c += stride) {
        float conf = pred[(size_t)c * ND + 4];
        if (mask[c]) {
            obj_s += softplus_f(-conf);
            nobj  += 1.0f;
        } else {
            noobj_s += softplus_f(conf);
        }
    }

    #pragma unroll
    for (int off = 32; off; off >>= 1) {
        obj_s   += __shfl_xor(obj_s,   off, 64);
        noobj_s += __shfl_xor(noobj_s, off, 64);
        nobj    += __shfl_xor(nobj,    off, 64);
    }

    __shared__ float sh[3];
    if (threadIdx.x == 0) { sh[0] = 0.0f; sh[1] = 0.0f; sh[2] = 0.0f; }
    __syncthreads();
    if ((threadIdx.x & 63) == 0) {
        atomicAdd(&sh[0], obj_s);
        atomicAdd(&sh[1], noobj_s);
        atomicAdd(&sh[2], nobj);
    }
    __syncthreads();
    if (threadIdx.x == 0) {
        atomicAdd(&acc[2], sh[0]);
        atomicAdd(&acc[3], sh[1]);
        atomicAdd(&acc[4], sh[2]);
    }
}

// Kernel 4: combine
__global__ void final_kernel(const float* __restrict__ acc,
                             float* __restrict__ out) {
    if (threadIdx.x == 0 && blockIdx.x == 0) {
        float coord = acc[0];
        float cls   = acc[1];
        float objs  = acc[2];
        float noobj = acc[3];
        float nobj  = acc[4];
        float nno   = (float)NCELL - nobj;

        float conf_obj   = objs  / fmaxf(nobj, 1.0f);
        float conf_noobj = noobj / fmaxf(nno,  1.0f);
        const float num_obj = (float)(NB * NT); // 3200

        float total = 5.0f * coord / num_obj
                    + conf_obj / num_obj
                    + 0.5f * conf_noobj / fmaxf(nno, 1.0f)   // double division, per reference
                    + cls / num_obj;
        out[0] = total;
    }
}

extern "C" void kernel_launch(void* const* d_in, const int* in_sizes, int n_in,
                              void* d_out, int out_size, void* d_ws, size_t ws_size,
                              hipStream_t stream) {
    const float* pred = (const float*)d_in[0];
    const float* tgt  = (const float*)d_in[1];

    unsigned char* mask = (unsigned char*)d_ws;          // NCELL bytes (409600, 64-aligned)
    float* acc = (float*)((char*)d_ws + NCELL);          // 5 floats

    hipMemsetAsync(d_ws, 0, NCELL + 64, stream);

    mark_kernel<<<(NTGT + 255) / 256, 256, 0, stream>>>(tgt, mask);
    target_kernel<<<50, 256, 0, stream>>>(pred, tgt, acc);
    conf_kernel<<<800, 256, 0, stream>>>(pred, mask, acc);
    final_kernel<<<1, 64, 0, stream>>>(acc, (float*)d_out);
}

// Round 2
// 52.485 us; speedup vs baseline: 1.4852x; 1.4852x over previous
//
#include <hip/hip_runtime.h>
#include <math.h>

// Problem constants (fixed by setup_inputs):
// B=64, H=W=80, HW=6400, T=50, C=80, D=5+C=85
#define NB    64
#define NH    80
#define NW    80
#define NHW   6400
#define NT    50
#define ND    85
#define NCELL (NB * NHW)   // 409600
#define NTGT  (NB * NT)    // 3200

__device__ __forceinline__ float softplus_f(float x) {
    // matches jax.nn.softplus = logaddexp(x, 0)
    return fmaxf(x, 0.0f) + log1pf(expf(-fabsf(x)));
}

// acc layout (floats in d_ws):
// [0] coord_sum  [1] cls_sum  [2] obj_softplus(-conf) sum  [3] n_obj_cells
// [4] softplus(+conf) at obj cells (correction)  [5] all-cells softplus(conf)
__global__ void init_kernel(float* __restrict__ acc) {
    if (threadIdx.x < 8) acc[threadIdx.x] = 0.0f;
}

// One block per batch: dedup obj cells + obj-conf terms + per-target losses.
__global__ void batch_kernel(const float* __restrict__ pred,
                             const float* __restrict__ tgt,
                             float* __restrict__ acc) {
    const int b = blockIdx.x;
    __shared__ int   s_gi[NT];
    __shared__ float s_red[5];   // coord, cls, obj_sp, cnt, corr

    if (threadIdx.x < 5) s_red[threadIdx.x] = 0.0f;

    const int t = threadIdx.x;
    if (t < NT) {
        const float* tp = tgt + ((size_t)b * NT + t) * 5;
        int gx = (int)floorf(tp[1] * (float)NW);
        int gy = (int)floorf(tp[2] * (float)NH);
        s_gi[t] = gy * NW + gx;
    }
    __syncthreads();

    // --- unique-obj-cell terms (threads 0..49) ---
    if (t < NT) {
        int gi = s_gi[t];
        bool uniq = true;
        for (int j = 0; j < t; ++j)
            if (s_gi[j] == gi) { uniq = false; break; }
        if (uniq) {
            float conf = pred[((size_t)b * NHW + gi) * ND + 4];
            atomicAdd(&s_red[2], softplus_f(-conf));
            atomicAdd(&s_red[3], 1.0f);
            atomicAdd(&s_red[4], softplus_f(conf));
        }
    }

    // --- per-target xy/wh/cls losses: one 64-lane wave per target ---
    const int lane = threadIdx.x & 63;
    const int wib  = threadIdx.x >> 6;   // 4 waves/block
    float coord_sum = 0.0f, cls_sum = 0.0f;

    for (int i = wib; i < NT; i += 4) {
        const float* tp = tgt + ((size_t)b * NT + i) * 5;
        float cid_f = tp[0], cx = tp[1], cy = tp[2], w = tp[3], h = tp[4];
        int gx = (int)floorf(cx * (float)NW);
        int gy = (int)floorf(cy * (float)NH);
        int gi = gy * NW + gx;
        const float* g = pred + ((size_t)b * NHW + gi) * ND;

        float e0 = g[lane];
        float e1 = (lane < ND - 64) ? g[64 + lane] : 0.0f;

        // log-softmax over class logits g[5..84]
        float v0 = (lane >= 5)      ? e0 : -3.4e38f;
        float v1 = (lane < ND - 64) ? e1 : -3.4e38f;
        float m = fmaxf(v0, v1);
        #pragma unroll
        for (int off = 32; off; off >>= 1) m = fmaxf(m, __shfl_xor(m, off, 64));
        float s = ((lane >= 5)      ? expf(e0 - m) : 0.0f)
                + ((lane < ND - 64) ? expf(e1 - m) : 0.0f);
        #pragma unroll
        for (int off = 32; off; off >>= 1) s += __shfl_xor(s, off, 64);

        float g0 = __shfl(e0, 0, 64);
        float g1 = __shfl(e0, 1, 64);
        float g2 = __shfl(e0, 2, 64);
        float g3 = __shfl(e0, 3, 64);

        if (lane == 0) {
            int cid = (int)cid_f;
            float gsel = g[5 + cid];
            cls_sum += -(gsel - m - logf(s));

            float px = 1.0f / (1.0f + expf(-g0));
            float py = 1.0f / (1.0f + expf(-g1));
            float tx = cx * (float)NW - (float)gx;
            float ty = cy * (float)NH - (float)gy;
            float tw = logf(w * (float)NW + 1e-16f);
            float th = logf(h * (float)NH + 1e-16f);
            float xy = 0.5f * ((px - tx) * (px - tx) + (py - ty) * (py - ty));
            float wh = 0.5f * ((g2 - tw) * (g2 - tw) + (g3 - th) * (g3 - th));
            coord_sum += xy + wh;
        }
    }

    if (lane == 0) {
        atomicAdd(&s_red[0], coord_sum);
        atomicAdd(&s_red[1], cls_sum);
    }
    __syncthreads();

    if (threadIdx.x == 0) {
        atomicAdd(&acc[0], s_red[0]);
        atomicAdd(&acc[1], s_red[1]);
        atomicAdd(&acc[2], s_red[2]);
        atomicAdd(&acc[3], s_red[3]);
        atomicAdd(&acc[4], s_red[4]);
    }
}

// All-cells softplus(conf) sum — pure streaming, no mask, no branch.
__global__ void conf_kernel(const float* __restrict__ pred,
                            float* __restrict__ acc) {
    int tid    = blockIdx.x * blockDim.x + threadIdx.x;
    int stride = gridDim.x * blockDim.x;

    float s = 0.0f;
    for (int c = tid; c < NCELL; c += stride)
        s += softplus_f(pred[(size_t)c * ND + 4]);

    #pragma unroll
    for (int off = 32; off; off >>= 1) s += __shfl_xor(s, off, 64);

    __shared__ float sh;
    if (threadIdx.x == 0) sh = 0.0f;
    __syncthreads();
    if ((threadIdx.x & 63) == 0) atomicAdd(&sh, s);
    __syncthreads();
    if (threadIdx.x == 0) atomicAdd(&acc[5], sh);
}

__global__ void final_kernel(const float* __restrict__ acc,
                             float* __restrict__ out) {
    if (threadIdx.x == 0 && blockIdx.x == 0) {
        float coord = acc[0];
        float cls   = acc[1];
        float objs  = acc[2];
        float nobj  = acc[3];
        float corr  = acc[4];
        float allsp = acc[5];

        float noobj = allsp - corr;
        float nno   = (float)NCELL - nobj;

        float conf_obj   = objs  / fmaxf(nobj, 1.0f);
        float conf_noobj = noobj / fmaxf(nno,  1.0f);
        const float num_obj = (float)(NB * NT); // 3200

        float total = 5.0f * coord / num_obj
                    + conf_obj / num_obj
                    + 0.5f * conf_noobj / fmaxf(nno, 1.0f)   // double division, per reference
                    + cls / num_obj;
        out[0] = total;
    }
}

extern "C" void kernel_launch(void* const* d_in, const int* in_sizes, int n_in,
                              void* d_out, int out_size, void* d_ws, size_t ws_size,
                              hipStream_t stream) {
    const float* pred = (const float*)d_in[0];
    const float* tgt  = (const float*)d_in[1];
    float* acc = (float*)d_ws;

    init_kernel <<<1, 64, 0, stream>>>(acc);
    batch_kernel<<<NB, 256, 0, stream>>>(pred, tgt, acc);
    conf_kernel <<<800, 256, 0, stream>>>(pred, acc);
    final_kernel<<<1, 64, 0, stream>>>(acc, (float*)d_out);
}

// Round 3
// 19.274 us; speedup vs baseline: 4.0444x; 2.7232x over previous
//
#include <hip/hip_runtime.h>
#include <math.h>

// Problem constants (fixed by setup_inputs):
// B=64, H=W=80, HW=6400, T=50, C=80, D=5+C=85
#define NB    64
#define NH    80
#define NW    80
#define NHW   6400
#define NT    50
#define ND    85
#define NCELL (NB * NHW)   // 409600
#define NTGT  (NB * NT)    // 3200
#define GRID  800          // main-kernel blocks; 800*256 = 204800 = NCELL/2
// partial layout per block: [0]=coord [1]=cls [2]=obj_sp [3]=cnt [4]=corr [5]=conf_all

__device__ __forceinline__ float softplus_f(float x) {
    return fmaxf(x, 0.0f) + log1pf(expf(-fabsf(x)));   // jax.nn.softplus
}

__global__ __launch_bounds__(256)
void main_kernel(const float* __restrict__ pred,
                 const float* __restrict__ tgt,
                 float* __restrict__ partials) {
    const int bid  = blockIdx.x;
    const int tid  = threadIdx.x;
    const int lane = tid & 63;
    const int wib  = tid >> 6;                 // 4 waves/block

    __shared__ float s_red[6];
    if (tid < 6) s_red[tid] = 0.0f;
    __syncthreads();

    // ---------------- per-target work: one wave per target ----------------
    {
        const int i = bid * 4 + wib;           // target index in [0, 3200)
        // GRID*4 = 3200 == NTGT exactly
        const int b = i / NT;
        const int t = i - b * NT;

        const float* tp = tgt + (size_t)i * 5;
        float tv = (lane < 5) ? tp[lane] : 0.0f;
        float cid_f = __shfl(tv, 0, 64);
        float cx    = __shfl(tv, 1, 64);
        float cy    = __shfl(tv, 2, 64);
        float w     = __shfl(tv, 3, 64);
        float h     = __shfl(tv, 4, 64);

        int gx = (int)floorf(cx * (float)NW);
        int gy = (int)floorf(cy * (float)NH);
        int gi = gy * NW + gx;

        // dedup: lane j (< t) recomputes gi of earlier target j in this batch
        bool match = false;
        if (lane < t) {
            const float* tj = tgt + ((size_t)b * NT + lane) * 5;
            int gxj = (int)floorf(tj[1] * (float)NW);
            int gyj = (int)floorf(tj[2] * (float)NH);
            match = (gyj * NW + gxj) == gi;
        }
        bool unique = (__ballot(match) == 0ull);

        // gather the 85-float prediction row (coalesced within the wave)
        const float* g = pred + ((size_t)b * NHW + gi) * ND;
        float e0 = g[lane];
        float e1 = (lane < ND - 64) ? g[64 + lane] : 0.0f;

        // log-softmax over class logits g[5..84]
        float v0 = (lane >= 5)      ? e0 : -3.4e38f;
        float v1 = (lane < ND - 64) ? e1 : -3.4e38f;
        float m = fmaxf(v0, v1);
        #pragma unroll
        for (int off = 32; off; off >>= 1) m = fmaxf(m, __shfl_xor(m, off, 64));
        float s = ((lane >= 5)      ? expf(e0 - m) : 0.0f)
                + ((lane < ND - 64) ? expf(e1 - m) : 0.0f);
        #pragma unroll
        for (int off = 32; off; off >>= 1) s += __shfl_xor(s, off, 64);

        // broadcasts from the row
        float g0   = __shfl(e0, 0, 64);
        float g1   = __shfl(e0, 1, 64);
        float g2   = __shfl(e0, 2, 64);
        float g3   = __shfl(e0, 3, 64);
        float conf = __shfl(e0, 4, 64);
        int   cid  = (int)cid_f;               // wave-uniform
        int   idx  = 5 + cid;                  // [5,85)
        int   li   = (idx < 64) ? idx : idx - 64;
        float sA   = __shfl(e0, li, 64);
        float sB   = __shfl(e1, li, 64);
        float gsel = (idx < 64) ? sA : sB;

        if (lane == 0) {
            float cls_v = -(gsel - m - logf(s));

            float px = 1.0f / (1.0f + expf(-g0));
            float py = 1.0f / (1.0f + expf(-g1));
            float tx = cx * (float)NW - (float)gx;
            float ty = cy * (float)NH - (float)gy;
            float tw = logf(w * (float)NW + 1e-16f);
            float th = logf(h * (float)NH + 1e-16f);
            float xy = 0.5f * ((px - tx) * (px - tx) + (py - ty) * (py - ty));
            float wh = 0.5f * ((g2 - tw) * (g2 - tw) + (g3 - th) * (g3 - th));

            atomicAdd(&s_red[0], xy + wh);
            atomicAdd(&s_red[1], cls_v);
            if (unique) {
                atomicAdd(&s_red[2], softplus_f(-conf));
                atomicAdd(&s_red[3], 1.0f);
                atomicAdd(&s_red[4], softplus_f(conf));
            }
        }
    }

    // ---------------- conf streaming: 2 cells per thread ----------------
    {
        int c0 = bid * 256 + tid;              // [0, 204800)
        float s = softplus_f(pred[(size_t)c0 * ND + 4])
                + softplus_f(pred[((size_t)c0 + 204800) * ND + 4]);
        #pragma unroll
        for (int off = 32; off; off >>= 1) s += __shfl_xor(s, off, 64);
        if (lane == 0) atomicAdd(&s_red[5], s);
    }

    __syncthreads();
    if (tid < 6) partials[(size_t)bid * 6 + tid] = s_red[tid];
}

__global__ __launch_bounds__(256)
void final_kernel(const float* __restrict__ partials,
                  float* __restrict__ out) {
    const int tid  = threadIdx.x;
    const int lane = tid & 63;
    const int wib  = tid >> 6;

    float a[6] = {0, 0, 0, 0, 0, 0};
    for (int r = tid; r < GRID; r += 256) {
        #pragma unroll
        for (int k = 0; k < 6; ++k) a[k] += partials[(size_t)r * 6 + k];
    }
    #pragma unroll
    for (int k = 0; k < 6; ++k) {
        #pragma unroll
        for (int off = 32; off; off >>= 1) a[k] += __shfl_xor(a[k], off, 64);
    }

    __shared__ float sh[4][6];
    if (lane == 0) {
        #pragma unroll
        for (int k = 0; k < 6; ++k) sh[wib][k] = a[k];
    }
    __syncthreads();

    if (tid == 0) {
        float coord = sh[0][0] + sh[1][0] + sh[2][0] + sh[3][0];
        float cls   = sh[0][1] + sh[1][1] + sh[2][1] + sh[3][1];
        float objs  = sh[0][2] + sh[1][2] + sh[2][2] + sh[3][2];
        float nobj  = sh[0][3] + sh[1][3] + sh[2][3] + sh[3][3];
        float corr  = sh[0][4] + sh[1][4] + sh[2][4] + sh[3][4];
        float allsp = sh[0][5] + sh[1][5] + sh[2][5] + sh[3][5];

        float noobj = allsp - corr;
        float nno   = (float)NCELL - nobj;

        float conf_obj   = objs  / fmaxf(nobj, 1.0f);
        float conf_noobj = noobj / fmaxf(nno,  1.0f);
        const float num_obj = (float)(NB * NT);   // 3200

        out[0] = 5.0f * coord / num_obj
               + conf_obj / num_obj
               + 0.5f * conf_noobj / fmaxf(nno, 1.0f)   // double division, per reference
               + cls / num_obj;
    }
}

extern "C" void kernel_launch(void* const* d_in, const int* in_sizes, int n_in,
                              void* d_out, int out_size, void* d_ws, size_t ws_size,
                              hipStream_t stream) {
    const float* pred = (const float*)d_in[0];
    const float* tgt  = (const float*)d_in[1];
    float* partials   = (float*)d_ws;             // GRID*6 floats = 19.2 KB

    main_kernel <<<GRID, 256, 0, stream>>>(pred, tgt, partials);
    final_kernel<<<1,    256, 0, stream>>>(partials, (float*)d_out);
}